// Round 14
// baseline (1329.170 us; speedup 1.0000x reference)
//
#include <hip/hip_runtime.h>
#include <hip/hip_bf16.h>
#include <stdint.h>

#define E_  1024
#define H_  16
#define D_  64
#define K_  8
#define B_  4
#define S_  2048
#define KH_ 128   // K_*H_
#define NB_ 512   // persistent grid size

typedef __attribute__((ext_vector_type(8))) short   short8;
typedef __attribute__((ext_vector_type(8))) ushort  ushort8;
typedef __attribute__((ext_vector_type(4))) ushort  ushort4v;
typedef __attribute__((ext_vector_type(4))) float   f32x4;

__device__ __forceinline__ ushort f2bf(float x){
  union { float f; uint32_t u; } v; v.f = x;
  return (ushort)((v.u + 0x7FFFu + ((v.u >> 16) & 1u)) >> 16);
}
__device__ __forceinline__ float bf2f(ushort u){
  union { uint32_t u32; float f; } v; v.u32 = ((uint32_t)u) << 16; return v.f;
}

__device__ __forceinline__ void lds_barrier(){
  asm volatile("s_waitcnt lgkmcnt(0)" ::: "memory");
  __builtin_amdgcn_s_barrier();
}

// device-scope grid barrier (all NB_ blocks co-resident by launch_bounds)
__device__ __forceinline__ void grid_sync(uint* cnt, uint* gen){
  __threadfence();
  __syncthreads();
  if (threadIdx.x == 0){
    uint g = __hip_atomic_load(gen, __ATOMIC_RELAXED, __HIP_MEMORY_SCOPE_AGENT);
    uint a = __hip_atomic_fetch_add(cnt, 1u, __ATOMIC_ACQ_REL, __HIP_MEMORY_SCOPE_AGENT);
    if (a == (uint)(NB_ - 1)){
      __hip_atomic_store(cnt, 0u, __ATOMIC_RELAXED, __HIP_MEMORY_SCOPE_AGENT);
      __hip_atomic_fetch_add(gen, 1u, __ATOMIC_RELEASE, __HIP_MEMORY_SCOPE_AGENT);
    } else {
      while (__hip_atomic_load(gen, __ATOMIC_ACQUIRE, __HIP_MEMORY_SCOPE_AGENT) == g)
        __builtin_amdgcn_s_sleep(1);
    }
  }
  __syncthreads();
  __threadfence();
}

__global__ __launch_bounds__(256, 2)
void mega(const float* __restrict__ rep,     const float* __restrict__ mask,
          const float* __restrict__ queries, const float* __restrict__ Wq,
          const float* __restrict__ bq,      const float* __restrict__ Wk,
          const float* __restrict__ bk,      const float* __restrict__ Wv,
          const float* __restrict__ bv,      const float* __restrict__ Wo,
          const float* __restrict__ bo,      const float* __restrict__ Wp,
          const float* __restrict__ bp,      const float* __restrict__ gamma,
          const float* __restrict__ beta,    float* __restrict__ out,
          float* qs, ushort* qkb, float* qb, ushort* scoresPb, ushort* probs,
          ushort* wrepPb, float* wrep, float* ctx, float* attn, float* outkb,
          uint* bar_cnt, uint* bar_gen){
  __shared__ __align__(16) char smem[30720];
  const int pb = blockIdx.x;
  const int t  = threadIdx.x;
  const int lane = t & 63;

  // ---------------- Phase A (k1): qs ----------------
  for (int i = 0; i < 4; i++){
    int vb = i*NB_ + pb;
    int gw = (vb * 256 + t) >> 6;
    int k = gw >> 10, f = gw & 1023;
    const float* wrow = Wq + ((size_t)(k*E_) + f)*E_;
    const float* qrow = queries + k*E_;
    float acc = 0.f;
    #pragma unroll
    for (int j = 0; j < 4; j++){
      int e = (j*64 + lane)*4;
      float4 w = *(const float4*)(wrow + e);
      float4 q = *(const float4*)(qrow + e);
      acc += w.x*q.x + w.y*q.y + w.z*q.z + w.w*q.w;
    }
    #pragma unroll
    for (int off = 32; off; off >>= 1) acc += __shfl_down(acc, off);
    if (lane == 0) qs[k*E_ + f] = (acc + bq[k*E_ + f]) * 0.125f;
  }
  grid_sync(bar_cnt, bar_gen);

  // ---------------- Phase B (k2): qkb, qb ----------------
  {
    float* qsh = (float*)smem;
    int eq = pb & 3;
    int kh = pb >> 2;
    int k = kh >> 4, h = kh & 15;
    if (t < 64) qsh[t] = qs[k*E_ + h*64 + t];
    __syncthreads();
    int e = eq*256 + t;
    const float* wbase = Wk + ((size_t)(k*E_) + h*64)*E_ + e;
    float a = 0.f;
    #pragma unroll 8
    for (int d = 0; d < 64; d++) a += qsh[d] * wbase[(size_t)d*E_];
    qkb[kh*E_ + e] = f2bf(a);
    if (eq == 0 && t == 0){
      float s = 0.f;
      for (int d = 0; d < 64; d++) s += qsh[d] * bk[k*E_ + h*64 + d];
      qb[kh] = s;
    }
  }
  grid_sync(bar_cnt, bar_gen);

  // ---------------- Phase C (k3): scoresPb ----------------
  {
    ushort (*As)[40] = (ushort(*)[40])(smem);           // [2*64][40]
    ushort (*Bs)[40] = (ushort(*)[40])(smem + 10240);   // [2*128][40]
    int ks = pb & 3, m = (pb >> 2) & 31, b = pb >> 7;
    int wv = t >> 6;
    int l0 = lane & 15, l1 = lane >> 4;
    int wr = wv >> 1, wc = wv & 1;
    int arow = t >> 2, acg = t & 3;
    int brow = t >> 1, bhalf = t & 1;
    const float*  aSrc = rep + ((size_t)(b*S_) + m*64 + arow)*E_ + ks*256 + acg*4;
    const ushort* bSrc = qkb + (size_t)brow*E_ + ks*256 + bhalf*16;

    f32x4 acc[2][4];
    #pragma unroll
    for (int mt = 0; mt < 2; mt++)
      #pragma unroll
      for (int nt = 0; nt < 4; nt++) acc[mt][nt] = (f32x4){0.f,0.f,0.f,0.f};

    float4  va[2][2];
    ushort8 vb8[2][2];
    #pragma unroll
    for (int p = 0; p < 2; p++){
      va[p][0]  = *(const float4*)(aSrc + p*32);
      va[p][1]  = *(const float4*)(aSrc + p*32 + 16);
      vb8[p][0] = *(const ushort8*)(bSrc + p*32);
      vb8[p][1] = *(const ushort8*)(bSrc + p*32 + 8);
    }
    #pragma unroll
    for (int j = 0; j < 2; j++){
      ushort4v u;
      u[0]=f2bf(va[0][j].x); u[1]=f2bf(va[0][j].y); u[2]=f2bf(va[0][j].z); u[3]=f2bf(va[0][j].w);
      *(ushort4v*)&As[arow][acg*4 + j*16] = u;
      *(ushort8*)&Bs[brow][bhalf*16 + j*8] = vb8[0][j];
    }
    lds_barrier();

    #pragma unroll
    for (int c = 0; c < 8; c++){
      const int cur = c & 1;
      short8 af[2], bf[4];
      #pragma unroll
      for (int mt = 0; mt < 2; mt++)
        af[mt] = *(const short8*)&As[cur*64 + wr*32 + mt*16 + l0][l1*8];
      #pragma unroll
      for (int nt = 0; nt < 4; nt++)
        bf[nt] = *(const short8*)&Bs[cur*128 + wc*64 + nt*16 + l0][l1*8];
      #pragma unroll
      for (int mt = 0; mt < 2; mt++)
        #pragma unroll
        for (int nt = 0; nt < 4; nt++)
          acc[mt][nt] = __builtin_amdgcn_mfma_f32_16x16x32_bf16(af[mt], bf[nt], acc[mt][nt], 0,0,0);
      if (c < 6){
        const int p = c & 1;
        va[p][0]  = *(const float4*)(aSrc + (c+2)*32);
        va[p][1]  = *(const float4*)(aSrc + (c+2)*32 + 16);
        vb8[p][0] = *(const ushort8*)(bSrc + (c+2)*32);
        vb8[p][1] = *(const ushort8*)(bSrc + (c+2)*32 + 8);
      }
      if (c < 7){
        const int p = (c+1) & 1;
        #pragma unroll
        for (int j = 0; j < 2; j++){
          ushort4v u;
          u[0]=f2bf(va[p][j].x); u[1]=f2bf(va[p][j].y); u[2]=f2bf(va[p][j].z); u[3]=f2bf(va[p][j].w);
          *(ushort4v*)&As[p*64 + arow][acg*4 + j*16] = u;
          *(ushort8*)&Bs[p*128 + brow][bhalf*16 + j*8] = vb8[p][j];
        }
      }
      lds_barrier();
    }
    ushort* obase = scoresPb + (size_t)ks*((size_t)B_*KH_*S_) + (size_t)(b*KH_)*S_;
    #pragma unroll
    for (int mt = 0; mt < 2; mt++){
      #pragma unroll
      for (int nt = 0; nt < 4; nt++){
        int kh = wc*64 + nt*16 + l0;
        int s  = m*64 + wr*32 + mt*16 + l1*4;
        ushort4v u;
        u[0] = f2bf(acc[mt][nt][0]);
        u[1] = f2bf(acc[mt][nt][1]);
        u[2] = f2bf(acc[mt][nt][2]);
        u[3] = f2bf(acc[mt][nt][3]);
        *(ushort4v*)(obase + (size_t)kh*S_ + s) = u;
      }
    }
  }
  grid_sync(bar_cnt, bar_gen);

  // ---------------- Phase D (k4): softmax -> probs ----------------
  {
    float* red = (float*)smem;
    const size_t P = (size_t)B_*KH_*S_;
    int row = pb;
    int b = row >> 7, kh = row & 127;
    int wv = t >> 6;
    const ushort* x = scoresPb + (size_t)row * S_ + t*8;
    const float* mrow = mask + b*S_ + t*8;
    float qbv = qb[kh];
    float v[8] = {0.f,0.f,0.f,0.f,0.f,0.f,0.f,0.f};
    #pragma unroll
    for (int p = 0; p < 4; p++){
      ushort8 up = *(const ushort8*)(x + (size_t)p*P);
      #pragma unroll
      for (int i = 0; i < 8; i++) v[i] += bf2f(up[i]);
    }
    {
      float4 m0 = *(const float4*)(mrow);
      float4 m1 = *(const float4*)(mrow + 4);
      v[0] += qbv + m0.x; v[1] += qbv + m0.y; v[2] += qbv + m0.z; v[3] += qbv + m0.w;
      v[4] += qbv + m1.x; v[5] += qbv + m1.y; v[6] += qbv + m1.z; v[7] += qbv + m1.w;
    }
    float m = v[0];
    #pragma unroll
    for (int i = 1; i < 8; i++) m = fmaxf(m, v[i]);
    #pragma unroll
    for (int off = 32; off; off >>= 1) m = fmaxf(m, __shfl_down(m, off));
    if (lane == 0) red[wv] = m;
    __syncthreads();
    float M = fmaxf(fmaxf(red[0], red[1]), fmaxf(red[2], red[3]));
    __syncthreads();
    float s = 0.f;
    #pragma unroll
    for (int i = 0; i < 8; i++){ v[i] = __expf(v[i] - M); s += v[i]; }
    #pragma unroll
    for (int off = 32; off; off >>= 1) s += __shfl_down(s, off);
    if (lane == 0) red[wv] = s;
    __syncthreads();
    float inv = 1.0f / (red[0] + red[1] + red[2] + red[3]);
    ushort8 o;
    #pragma unroll
    for (int i = 0; i < 8; i++) o[i] = f2bf(v[i] * inv);
    *(ushort8*)(probs + (size_t)row*S_ + t*8) = o;
  }
  grid_sync(bar_cnt, bar_gen);

  // ---------------- Phase E (k5): wrepPb ----------------
  {
    ushort (*As)[40] = (ushort(*)[40])(smem);           // [2*128][40]
    ushort (*Bs)[40] = (ushort(*)[40])(smem + 20480);   // [2*64][40]
    int et = pb & 15, b = (pb >> 4) & 3, sp = pb >> 6;
    int wv = t >> 6;
    int l0 = lane & 15, l1 = lane >> 4;
    int wr = wv >> 1, wc = wv & 1;
    int arow = t >> 1, ahalf = t & 1;
    int bsrow = t >> 3, beg = t & 7;
    const ushort* aSrc = probs + (size_t)(b*KH_ + arow)*S_ + sp*256 + ahalf*16;
    const float*  bSrc = rep + ((size_t)(b*S_) + sp*256 + bsrow)*E_ + et*64 + beg*8;

    f32x4 acc[4][2];
    #pragma unroll
    for (int mt = 0; mt < 4; mt++)
      #pragma unroll
      for (int nt = 0; nt < 2; nt++) acc[mt][nt] = (f32x4){0.f,0.f,0.f,0.f};

    ushort8 va[2][2];
    float4  vb8[2][2];
    #pragma unroll
    for (int p = 0; p < 2; p++){
      va[p][0]  = *(const ushort8*)(aSrc + p*32);
      va[p][1]  = *(const ushort8*)(aSrc + p*32 + 8);
      vb8[p][0] = *(const float4*)(bSrc + (size_t)(p*32)*E_);
      vb8[p][1] = *(const float4*)(bSrc + (size_t)(p*32)*E_ + 4);
    }
    {
      *(ushort8*)&As[arow][ahalf*16]     = va[0][0];
      *(ushort8*)&As[arow][ahalf*16 + 8] = va[0][1];
      int rot = (beg & 3) * 8;
      int sw = (bsrow + rot) & 31;
      #pragma unroll
      for (int j = 0; j < 2; j++){
        float vv[4] = {vb8[0][j].x, vb8[0][j].y, vb8[0][j].z, vb8[0][j].w};
        #pragma unroll
        for (int jj = 0; jj < 4; jj++)
          Bs[beg*8 + j*4 + jj][sw] = f2bf(vv[jj]);
      }
    }
    lds_barrier();

    #pragma unroll
    for (int c = 0; c < 8; c++){
      const int cur = c & 1;
      short8 af[4], bf[2];
      #pragma unroll
      for (int mt = 0; mt < 4; mt++)
        af[mt] = *(const short8*)&As[cur*128 + wr*64 + mt*16 + l0][l1*8];
      #pragma unroll
      for (int nt = 0; nt < 2; nt++){
        int e_loc = wc*32 + nt*16 + l0;
        int sstart = (l1*8 + ((e_loc >> 3) & 3)*8) & 31;
        bf[nt] = *(const short8*)&Bs[cur*64 + e_loc][sstart];
      }
      #pragma unroll
      for (int mt = 0; mt < 4; mt++)
        #pragma unroll
        for (int nt = 0; nt < 2; nt++)
          acc[mt][nt] = __builtin_amdgcn_mfma_f32_16x16x32_bf16(af[mt], bf[nt], acc[mt][nt], 0,0,0);
      if (c < 6){
        const int p = c & 1;
        va[p][0]  = *(const ushort8*)(aSrc + (c+2)*32);
        va[p][1]  = *(const ushort8*)(aSrc + (c+2)*32 + 8);
        vb8[p][0] = *(const float4*)(bSrc + (size_t)((c+2)*32)*E_);
        vb8[p][1] = *(const float4*)(bSrc + (size_t)((c+2)*32)*E_ + 4);
      }
      if (c < 7){
        const int p = (c+1) & 1;
        *(ushort8*)&As[p*128 + arow][ahalf*16]     = va[p][0];
        *(ushort8*)&As[p*128 + arow][ahalf*16 + 8] = va[p][1];
        int rot = (beg & 3) * 8;
        int sw = (bsrow + rot) & 31;
        #pragma unroll
        for (int j = 0; j < 2; j++){
          float vv[4] = {vb8[p][j].x, vb8[p][j].y, vb8[p][j].z, vb8[p][j].w};
          #pragma unroll
          for (int jj = 0; jj < 4; jj++)
            Bs[p*64 + beg*8 + j*4 + jj][sw] = f2bf(vv[jj]);
        }
      }
      lds_barrier();
    }
    ushort* obase = wrepPb + (size_t)sp*((size_t)B_*KH_*E_) + (size_t)(b*KH_)*E_ + et*64;
    #pragma unroll
    for (int mt = 0; mt < 4; mt++){
      #pragma unroll
      for (int nt = 0; nt < 2; nt++){
        int kh = wr*64 + mt*16 + l1*4;
        int e  = wc*32 + nt*16 + l0;
        #pragma unroll
        for (int r = 0; r < 4; r++)
          obase[(size_t)(kh + r)*E_ + e] = f2bf(acc[mt][nt][r]);
      }
    }
  }
  grid_sync(bar_cnt, bar_gen);

  // ---------------- Phase F (k6c): wrep = sum 8 partials ----------------
  {
    const size_t P = (size_t)B_*KH_*E_;
    size_t i = ((size_t)pb * 256 + t) * 4;
    float a[4] = {0.f,0.f,0.f,0.f};
    #pragma unroll
    for (int p = 0; p < 8; p++){
      ushort4v u = *(const ushort4v*)(wrepPb + i + (size_t)p*P);
      #pragma unroll
      for (int j = 0; j < 4; j++) a[j] += bf2f(u[j]);
    }
    f32x4 o = {a[0], a[1], a[2], a[3]};
    *(f32x4*)(wrep + i) = o;
  }
  grid_sync(bar_cnt, bar_gen);

  // ---------------- Phase G (k6x): ctx ----------------
  {
    float (*xs)[1024] = (float(*)[1024])smem;
    int fq = pb & 3, h = (pb >> 2) & 15, k = pb >> 6;
    #pragma unroll
    for (int i = 0; i < 4; i++){
      int idx = i*256 + t;
      int b = idx >> 8, e4 = (idx & 255)*4;
      *(f32x4*)&xs[b][e4] = *(const f32x4*)(wrep + ((size_t)(b*KH_) + k*16 + h)*E_ + e4);
    }
    __syncthreads();
    int wv = t >> 6;
    #pragma unroll
    for (int r = 0; r < 4; r++){
      int f = h*64 + fq*16 + wv*4 + r;
      const float* wrow = Wv + ((size_t)(k*E_) + f)*E_;
      float a0=0.f, a1=0.f, a2=0.f, a3=0.f;
      #pragma unroll
      for (int j = 0; j < 4; j++){
        int e = (j*64 + lane)*4;
        float4 w = *(const float4*)(wrow + e);
        float4 p;
        p = *(const float4*)&xs[0][e]; a0 += w.x*p.x + w.y*p.y + w.z*p.z + w.w*p.w;
        p = *(const float4*)&xs[1][e]; a1 += w.x*p.x + w.y*p.y + w.z*p.z + w.w*p.w;
        p = *(const float4*)&xs[2][e]; a2 += w.x*p.x + w.y*p.y + w.z*p.z + w.w*p.w;
        p = *(const float4*)&xs[3][e]; a3 += w.x*p.x + w.y*p.y + w.z*p.z + w.w*p.w;
      }
      #pragma unroll
      for (int off = 32; off; off >>= 1){
        a0 += __shfl_down(a0, off); a1 += __shfl_down(a1, off);
        a2 += __shfl_down(a2, off); a3 += __shfl_down(a3, off);
      }
      if (lane == 0){
        float bvv = bv[k*E_ + f];
        ctx[((size_t)(k*B_) + 0)*E_ + f] = a0 + bvv;
        ctx[((size_t)(k*B_) + 1)*E_ + f] = a1 + bvv;
        ctx[((size_t)(k*B_) + 2)*E_ + f] = a2 + bvv;
        ctx[((size_t)(k*B_) + 3)*E_ + f] = a3 + bvv;
      }
    }
  }
  grid_sync(bar_cnt, bar_gen);

  // ---------------- Phase H/I: two gemv16 stages ----------------
  #pragma unroll 1
  for (int stage = 0; stage < 2; stage++){
    const float* in   = stage == 0 ? ctx  : attn;
    const float* W    = stage == 0 ? Wo   : Wp;
    const float* bias = stage == 0 ? bo   : bp;
    float* outp       = stage == 0 ? attn : outkb;
    float (*xs)[1024] = (float(*)[1024])smem;
    int fg = pb & 63, k = pb >> 6;
    #pragma unroll
    for (int i = 0; i < 4; i++){
      int idx = i*256 + t;
      int b = idx >> 8, e4 = (idx & 255)*4;
      *(f32x4*)&xs[b][e4] = *(const f32x4*)(in + ((size_t)(k*B_) + b)*E_ + e4);
    }
    __syncthreads();
    int wv = t >> 6;
    #pragma unroll
    for (int r = 0; r < 4; r++){
      int f = fg*16 + wv*4 + r;
      const float* wrow = W + ((size_t)(k*E_) + f)*E_;
      float a0=0.f, a1=0.f, a2=0.f, a3=0.f;
      #pragma unroll
      for (int j = 0; j < 4; j++){
        int e = (j*64 + lane)*4;
        float4 w = *(const float4*)(wrow + e);
        float4 p;
        p = *(const float4*)&xs[0][e]; a0 += w.x*p.x + w.y*p.y + w.z*p.z + w.w*p.w;
        p = *(const float4*)&xs[1][e]; a1 += w.x*p.x + w.y*p.y + w.z*p.z + w.w*p.w;
        p = *(const float4*)&xs[2][e]; a2 += w.x*p.x + w.y*p.y + w.z*p.z + w.w*p.w;
        p = *(const float4*)&xs[3][e]; a3 += w.x*p.x + w.y*p.y + w.z*p.z + w.w*p.w;
      }
      #pragma unroll
      for (int off = 32; off; off >>= 1){
        a0 += __shfl_down(a0, off); a1 += __shfl_down(a1, off);
        a2 += __shfl_down(a2, off); a3 += __shfl_down(a3, off);
      }
      if (lane == 0){
        float bb = bias[k*E_ + f];
        outp[((size_t)(k*B_) + 0)*E_ + f] = a0 + bb;
        outp[((size_t)(k*B_) + 1)*E_ + f] = a1 + bb;
        outp[((size_t)(k*B_) + 2)*E_ + f] = a2 + bb;
        outp[((size_t)(k*B_) + 3)*E_ + f] = a3 + bb;
      }
    }
    grid_sync(bar_cnt, bar_gen);
  }

  // ---------------- Phase J (k9): LayerNorm ----------------
  if (pb < 32){
    float* rs  = (float*)smem;
    float* rs2 = rs + 4;
    int row = pb;
    int b = row >> 3, k = row & 7;
    int wv = t >> 6;
    const float* x = outkb + ((size_t)(k*B_) + b)*E_;
    float4 v = *(const float4*)(x + t*4);
    float s  = v.x + v.y + v.z + v.w;
    float s2 = v.x*v.x + v.y*v.y + v.z*v.z + v.w*v.w;
    #pragma unroll
    for (int off = 32; off; off >>= 1){ s += __shfl_down(s, off); s2 += __shfl_down(s2, off); }
    if (lane == 0){ rs[wv] = s; rs2[wv] = s2; }
    __syncthreads();
    float S  = rs[0] + rs[1] + rs[2] + rs[3];
    float S2 = rs2[0] + rs2[1] + rs2[2] + rs2[3];
    float mu = S * (1.0f/E_);
    float var = S2 * (1.0f/E_) - mu*mu;
    float inv = rsqrtf(var + 1e-5f);
    float4 g  = *(const float4*)(gamma + t*4);
    float4 bt = *(const float4*)(beta + t*4);
    float4 o;
    o.x = g.x*(v.x-mu)*inv + bt.x;
    o.y = g.y*(v.y-mu)*inv + bt.y;
    o.z = g.z*(v.z-mu)*inv + bt.z;
    o.w = g.w*(v.w-mu)*inv + bt.w;
    *(float4*)(out + ((size_t)(b*K_) + k)*E_ + t*4) = o;
  }
}

extern "C" void kernel_launch(void* const* d_in, const int* in_sizes, int n_in,
                              void* d_out, int out_size, void* d_ws, size_t ws_size,
                              hipStream_t stream){
  const float* rep     = (const float*)d_in[0];
  const float* mask    = (const float*)d_in[1];
  const float* queries = (const float*)d_in[2];
  const float* Wq = (const float*)d_in[3];
  const float* bq = (const float*)d_in[4];
  const float* Wk = (const float*)d_in[5];
  const float* bk = (const float*)d_in[6];
  const float* Wv = (const float*)d_in[7];
  const float* bv = (const float*)d_in[8];
  const float* Wo = (const float*)d_in[9];
  const float* bo = (const float*)d_in[10];
  const float* Wp = (const float*)d_in[11];
  const float* bp = (const float*)d_in[12];
  const float* gamma = (const float*)d_in[13];
  const float* beta  = (const float*)d_in[14];
  float* out = (float*)d_out;

  char* ws = (char*)d_ws;
  size_t off = 0;
  float*  qs      = (float*)(ws + off);  off += (size_t)K_*E_*4;
  ushort* qkb     = (ushort*)(ws + off); off += (size_t)KH_*E_*2;
  float*  qb      = (float*)(ws + off);  off += 1024;
  ushort* scoresPb= (ushort*)(ws + off); off += (size_t)4*B_*KH_*S_*2;
  ushort* probs   = (ushort*)(ws + off); off += (size_t)B_*KH_*S_*2;
  ushort* wrepPb  = (ushort*)(ws + off); off += (size_t)8*B_*KH_*E_*2;
  float*  wrep    = (float*)(ws + off);  off += (size_t)B_*KH_*E_*4;
  float*  ctx     = (float*)(ws + off);  off += (size_t)K_*B_*E_*4;
  float*  attn    = (float*)(ws + off);  off += (size_t)K_*B_*E_*4;
  float*  outkb   = (float*)(ws + off);  off += (size_t)K_*B_*E_*4;
  off = (off + 255) & ~(size_t)255;
  uint*   bar     = (uint*)(ws + off);   off += 256;

  hipMemsetAsync(bar, 0, 256, stream);
  mega<<<NB_, 256, 0, stream>>>(rep, mask, queries, Wq, bq, Wk, bk, Wv, bv,
                                Wo, bo, Wp, bp, gamma, beta, out,
                                qs, qkb, qb, scoresPb, probs, wrepPb, wrep,
                                ctx, attn, outkb, bar, bar + 1);
}

// Round 15
// 75.571 us; speedup vs baseline: 17.5884x; 17.5884x over previous
//
#include <hip/hip_runtime.h>
#include <hip/hip_bf16.h>
#include <stdint.h>

#define E_  1024
#define H_  16
#define D_  64
#define K_  8
#define B_  4
#define S_  2048
#define KH_ 128   // K_*H_

typedef __attribute__((ext_vector_type(8))) short   short8;
typedef __attribute__((ext_vector_type(8))) ushort  ushort8;
typedef __attribute__((ext_vector_type(4))) ushort  ushort4v;
typedef __attribute__((ext_vector_type(4))) float   f32x4;

__device__ __forceinline__ ushort f2bf(float x){
  union { float f; uint32_t u; } v; v.f = x;
  return (ushort)((v.u + 0x7FFFu + ((v.u >> 16) & 1u)) >> 16);
}
__device__ __forceinline__ float bf2f(ushort u){
  union { uint32_t u32; float f; } v; v.u32 = ((uint32_t)u) << 16; return v.f;
}

// raw producer barrier: ds_writes visible, but do NOT drain vmcnt (keeps
// the depth-2 global prefetch in flight across the barrier).
__device__ __forceinline__ void lds_barrier(){
  asm volatile("s_waitcnt lgkmcnt(0)" ::: "memory");
  __builtin_amdgcn_s_barrier();
}

// ---------------- K1: qs[k,f] = (queries[k,:]·Wq[k,f,:] + bq)*0.125 -------
__global__ __launch_bounds__(256) void k1_qs(const float* __restrict__ queries,
                                             const float* __restrict__ Wq,
                                             const float* __restrict__ bq,
                                             float* __restrict__ qs){
  int gw = (blockIdx.x * 256 + threadIdx.x) >> 6;
  int lane = threadIdx.x & 63;
  int k = gw >> 10, f = gw & 1023;
  const float* wrow = Wq + ((size_t)(k*E_) + f)*E_;
  const float* qrow = queries + k*E_;
  float acc = 0.f;
  #pragma unroll
  for (int j = 0; j < 4; j++){
    int e = (j*64 + lane)*4;
    float4 w = *(const float4*)(wrow + e);
    float4 q = *(const float4*)(qrow + e);
    acc += w.x*q.x + w.y*q.y + w.z*q.z + w.w*q.w;
  }
  #pragma unroll
  for (int off = 32; off; off >>= 1) acc += __shfl_down(acc, off);
  if (lane == 0) qs[k*E_ + f] = (acc + bq[k*E_ + f]) * 0.125f;
}

// ---------------- K2: qk[k,h,e] (bf16) and qb[k,h] ------------------------
__global__ __launch_bounds__(256) void k2_qk(const float* __restrict__ qs,
                                             const float* __restrict__ Wk,
                                             const float* __restrict__ bk,
                                             ushort* __restrict__ qkb,
                                             float* __restrict__ qb){
  int bid = blockIdx.x;
  int eq = bid & 3;
  int kh = bid >> 2;
  int k = kh >> 4, h = kh & 15;
  __shared__ float qsh[64];
  int t = threadIdx.x;
  if (t < 64) qsh[t] = qs[k*E_ + h*64 + t];
  __syncthreads();
  int e = eq*256 + t;
  const float* wbase = Wk + ((size_t)(k*E_) + h*64)*E_ + e;
  float a = 0.f;
  #pragma unroll 8
  for (int d = 0; d < 64; d++) a += qsh[d] * wbase[(size_t)d*E_];
  qkb[kh*E_ + e] = f2bf(a);
  if (eq == 0 && t == 0){
    float s = 0.f;
    for (int d = 0; d < 64; d++) s += qsh[d] * bk[k*E_ + h*64 + d];
    qb[kh] = s;
  }
}

// ---------------- K3: scoresPb[ks][b,kh,s] partial (bf16) = rep·qk --------
__global__ __launch_bounds__(256) void k3_scores(const float* __restrict__ rep,
                                                 const ushort* __restrict__ qkb,
                                                 ushort* __restrict__ scoresPb){
  __shared__ __align__(16) ushort As[2][64][40];
  __shared__ __align__(16) ushort Bs[2][128][40];
  int bid = blockIdx.x;
  int ks = bid & 3, m = (bid >> 2) & 31, b = bid >> 7;
  int t = threadIdx.x, wv = t >> 6, lane = t & 63;
  int l0 = lane & 15, l1 = lane >> 4;
  int wr = wv >> 1, wc = wv & 1;
  int arow = t >> 2, acg = t & 3;                 // A: 64 rows x (2 float4)
  int brow = t >> 1, bhalf = t & 1;               // B: 128 rows x (2 ushort8)
  const float*  aSrc = rep + ((size_t)(b*S_) + m*64 + arow)*E_ + ks*256 + acg*4;
  const ushort* bSrc = qkb + (size_t)brow*E_ + ks*256 + bhalf*16;

  f32x4 acc[2][4];
  #pragma unroll
  for (int mt = 0; mt < 2; mt++)
    #pragma unroll
    for (int nt = 0; nt < 4; nt++) acc[mt][nt] = (f32x4){0.f,0.f,0.f,0.f};

  float4  va[2][2];
  ushort8 vb[2][2];
  #pragma unroll
  for (int p = 0; p < 2; p++){
    va[p][0] = *(const float4*)(aSrc + p*32);
    va[p][1] = *(const float4*)(aSrc + p*32 + 16);
    vb[p][0] = *(const ushort8*)(bSrc + p*32);
    vb[p][1] = *(const ushort8*)(bSrc + p*32 + 8);
  }
  #pragma unroll
  for (int j = 0; j < 2; j++){
    ushort4v u;
    u[0]=f2bf(va[0][j].x); u[1]=f2bf(va[0][j].y); u[2]=f2bf(va[0][j].z); u[3]=f2bf(va[0][j].w);
    *(ushort4v*)&As[0][arow][acg*4 + j*16] = u;
    *(ushort8*)&Bs[0][brow][bhalf*16 + j*8] = vb[0][j];
  }
  lds_barrier();

  #pragma unroll
  for (int c = 0; c < 8; c++){
    const int cur = c & 1;
    short8 af[2], bf[4];
    #pragma unroll
    for (int mt = 0; mt < 2; mt++)
      af[mt] = *(const short8*)&As[cur][wr*32 + mt*16 + l0][l1*8];
    #pragma unroll
    for (int nt = 0; nt < 4; nt++)
      bf[nt] = *(const short8*)&Bs[cur][wc*64 + nt*16 + l0][l1*8];
    #pragma unroll
    for (int mt = 0; mt < 2; mt++)
      #pragma unroll
      for (int nt = 0; nt < 4; nt++)
        acc[mt][nt] = __builtin_amdgcn_mfma_f32_16x16x32_bf16(af[mt], bf[nt], acc[mt][nt], 0,0,0);
    if (c < 6){
      const int p = c & 1;
      va[p][0] = *(const float4*)(aSrc + (c+2)*32);
      va[p][1] = *(const float4*)(aSrc + (c+2)*32 + 16);
      vb[p][0] = *(const ushort8*)(bSrc + (c+2)*32);
      vb[p][1] = *(const ushort8*)(bSrc + (c+2)*32 + 8);
    }
    if (c < 7){
      const int p = (c+1) & 1;
      #pragma unroll
      for (int j = 0; j < 2; j++){
        ushort4v u;
        u[0]=f2bf(va[p][j].x); u[1]=f2bf(va[p][j].y); u[2]=f2bf(va[p][j].z); u[3]=f2bf(va[p][j].w);
        *(ushort4v*)&As[p][arow][acg*4 + j*16] = u;
        *(ushort8*)&Bs[p][brow][bhalf*16 + j*8] = vb[p][j];
      }
    }
    lds_barrier();
  }
  ushort* obase = scoresPb + (size_t)ks*((size_t)B_*KH_*S_) + (size_t)(b*KH_)*S_;
  #pragma unroll
  for (int mt = 0; mt < 2; mt++){
    #pragma unroll
    for (int nt = 0; nt < 4; nt++){
      int kh = wc*64 + nt*16 + l0;
      int s  = m*64 + wr*32 + mt*16 + l1*4;
      ushort4v u;
      u[0] = f2bf(acc[mt][nt][0]);
      u[1] = f2bf(acc[mt][nt][1]);
      u[2] = f2bf(acc[mt][nt][2]);
      u[3] = f2bf(acc[mt][nt][3]);
      *(ushort4v*)(obase + (size_t)kh*S_ + s) = u;
    }
  }
}

// ---------------- K4: softmax over 4 bf16 partials + qb + mask -> probs ---
__global__ __launch_bounds__(256) void k4_softmax(const ushort* __restrict__ scoresPb,
                                                  const float* __restrict__ qb,
                                                  const float* __restrict__ mask,
                                                  ushort* __restrict__ probs){
  __shared__ float red[4];
  const size_t P = (size_t)B_*KH_*S_;
  int row = blockIdx.x;            // b*KH + kh
  int b = row >> 7, kh = row & 127;
  int t = threadIdx.x, wv = t >> 6, lane = t & 63;
  const ushort* x = scoresPb + (size_t)row * S_ + t*8;
  const float* mrow = mask + b*S_ + t*8;
  float qbv = qb[kh];
  float v[8] = {0.f,0.f,0.f,0.f,0.f,0.f,0.f,0.f};
  #pragma unroll
  for (int p = 0; p < 4; p++){
    ushort8 up = *(const ushort8*)(x + (size_t)p*P);
    #pragma unroll
    for (int i = 0; i < 8; i++) v[i] += bf2f(up[i]);
  }
  {
    float4 m0 = *(const float4*)(mrow);
    float4 m1 = *(const float4*)(mrow + 4);
    v[0] += qbv + m0.x; v[1] += qbv + m0.y; v[2] += qbv + m0.z; v[3] += qbv + m0.w;
    v[4] += qbv + m1.x; v[5] += qbv + m1.y; v[6] += qbv + m1.z; v[7] += qbv + m1.w;
  }
  float m = v[0];
  #pragma unroll
  for (int i = 1; i < 8; i++) m = fmaxf(m, v[i]);
  #pragma unroll
  for (int off = 32; off; off >>= 1) m = fmaxf(m, __shfl_down(m, off));
  if (lane == 0) red[wv] = m;
  __syncthreads();
  float M = fmaxf(fmaxf(red[0], red[1]), fmaxf(red[2], red[3]));
  __syncthreads();
  float s = 0.f;
  #pragma unroll
  for (int i = 0; i < 8; i++){ v[i] = __expf(v[i] - M); s += v[i]; }
  #pragma unroll
  for (int off = 32; off; off >>= 1) s += __shfl_down(s, off);
  if (lane == 0) red[wv] = s;
  __syncthreads();
  float inv = 1.0f / (red[0] + red[1] + red[2] + red[3]);
  ushort8 o;
  #pragma unroll
  for (int i = 0; i < 8; i++) o[i] = f2bf(v[i] * inv);
  *(ushort8*)(probs + (size_t)row*S_ + t*8) = o;
}

// ---------------- K5: wrepPb[sp][b,kh,e] (bf16) = probs·rep ---------------
__global__ __launch_bounds__(256) void k5_wrep(const ushort* __restrict__ probs,
                                               const float* __restrict__ rep,
                                               ushort* __restrict__ wrepPb){
  __shared__ __align__(16) ushort As[2][128][40];
  __shared__ __align__(16) ushort Bs[2][64][40];
  int bid = blockIdx.x;
  int et = bid & 15, b = (bid >> 4) & 3, sp = bid >> 6;
  int t = threadIdx.x, wv = t >> 6, lane = t & 63;
  int l0 = lane & 15, l1 = lane >> 4;
  int wr = wv >> 1, wc = wv & 1;
  int arow = t >> 1, ahalf = t & 1;               // A: 128 rows x (2 ushort8)
  int bsrow = t >> 3, beg = t & 7;                // B: 32 s-rows x 8 e
  const ushort* aSrc = probs + (size_t)(b*KH_ + arow)*S_ + sp*256 + ahalf*16;
  const float*  bSrc = rep + ((size_t)(b*S_) + sp*256 + bsrow)*E_ + et*64 + beg*8;

  f32x4 acc[4][2];
  #pragma unroll
  for (int mt = 0; mt < 4; mt++)
    #pragma unroll
    for (int nt = 0; nt < 2; nt++) acc[mt][nt] = (f32x4){0.f,0.f,0.f,0.f};

  ushort8 va[2][2];
  float4  vb[2][2];
  #pragma unroll
  for (int p = 0; p < 2; p++){
    va[p][0] = *(const ushort8*)(aSrc + p*32);
    va[p][1] = *(const ushort8*)(aSrc + p*32 + 8);
    vb[p][0] = *(const float4*)(bSrc + (size_t)(p*32)*E_);
    vb[p][1] = *(const float4*)(bSrc + (size_t)(p*32)*E_ + 4);
  }
  {
    *(ushort8*)&As[0][arow][ahalf*16]     = va[0][0];
    *(ushort8*)&As[0][arow][ahalf*16 + 8] = va[0][1];
    int rot = (beg & 3) * 8;
    int sw = (bsrow + rot) & 31;
    #pragma unroll
    for (int j = 0; j < 2; j++){
      float vv[4] = {vb[0][j].x, vb[0][j].y, vb[0][j].z, vb[0][j].w};
      #pragma unroll
      for (int jj = 0; jj < 4; jj++)
        Bs[0][beg*8 + j*4 + jj][sw] = f2bf(vv[jj]);
    }
  }
  lds_barrier();

  #pragma unroll
  for (int c = 0; c < 8; c++){
    const int cur = c & 1;
    short8 af[4], bf[2];
    #pragma unroll
    for (int mt = 0; mt < 4; mt++)
      af[mt] = *(const short8*)&As[cur][wr*64 + mt*16 + l0][l1*8];
    #pragma unroll
    for (int nt = 0; nt < 2; nt++){
      int e_loc = wc*32 + nt*16 + l0;
      int sstart = (l1*8 + ((e_loc >> 3) & 3)*8) & 31;
      bf[nt] = *(const short8*)&Bs[cur][e_loc][sstart];
    }
    #pragma unroll
    for (int mt = 0; mt < 4; mt++)
      #pragma unroll
      for (int nt = 0; nt < 2; nt++)
        acc[mt][nt] = __builtin_amdgcn_mfma_f32_16x16x32_bf16(af[mt], bf[nt], acc[mt][nt], 0,0,0);
    if (c < 6){
      const int p = c & 1;
      va[p][0] = *(const ushort8*)(aSrc + (c+2)*32);
      va[p][1] = *(const ushort8*)(aSrc + (c+2)*32 + 8);
      vb[p][0] = *(const float4*)(bSrc + (size_t)((c+2)*32)*E_);
      vb[p][1] = *(const float4*)(bSrc + (size_t)((c+2)*32)*E_ + 4);
    }
    if (c < 7){
      const int p = (c+1) & 1;
      *(ushort8*)&As[p][arow][ahalf*16]     = va[p][0];
      *(ushort8*)&As[p][arow][ahalf*16 + 8] = va[p][1];
      int rot = (beg & 3) * 8;
      int sw = (bsrow + rot) & 31;
      #pragma unroll
      for (int j = 0; j < 2; j++){
        float vv[4] = {vb[p][j].x, vb[p][j].y, vb[p][j].z, vb[p][j].w};
        #pragma unroll
        for (int jj = 0; jj < 4; jj++)
          Bs[p][beg*8 + j*4 + jj][sw] = f2bf(vv[jj]);
      }
    }
    lds_barrier();
  }
  ushort* obase = wrepPb + (size_t)sp*((size_t)B_*KH_*E_) + (size_t)(b*KH_)*E_ + et*64;
  #pragma unroll
  for (int mt = 0; mt < 4; mt++){
    #pragma unroll
    for (int nt = 0; nt < 2; nt++){
      int kh = wr*64 + mt*16 + l1*4;
      int e  = wc*32 + nt*16 + l0;
      #pragma unroll
      for (int r = 0; r < 4; r++)
        obase[(size_t)(kh + r)*E_ + e] = f2bf(acc[mt][nt][r]);
    }
  }
}

// ---------------- K6c: wrep (f32) = sum of 8 bf16 partials ----------------
__global__ __launch_bounds__(256) void k6c_comb(const ushort* __restrict__ wrepPb,
                                                float* __restrict__ wrep){
  const size_t P = (size_t)B_*KH_*E_;
  size_t i = ((size_t)blockIdx.x * 256 + threadIdx.x) * 8;
  float a[8] = {0.f,0.f,0.f,0.f,0.f,0.f,0.f,0.f};
  #pragma unroll
  for (int p = 0; p < 8; p++){
    ushort8 u = *(const ushort8*)(wrepPb + i + (size_t)p*P);
    #pragma unroll
    for (int j = 0; j < 8; j++) a[j] += bf2f(u[j]);
  }
  f32x4 o0 = {a[0], a[1], a[2], a[3]};
  f32x4 o1 = {a[4], a[5], a[6], a[7]};
  *(f32x4*)(wrep + i)     = o0;
  *(f32x4*)(wrep + i + 4) = o1;
}

// ---------------- K6x: ctx[k,b,f] = wrep[b,kh(f),:]·Wv[k,f,:] + bv --------
// x staged in LDS once per block (16 f-rows/block).
// grid 512: k=bid>>6, h=(bid>>2)&15, fq=bid&3. 4 waves x 4 f each.
__global__ __launch_bounds__(256) void k6x_ctx(const float* __restrict__ wrep,
                                               const float* __restrict__ Wv,
                                               const float* __restrict__ bv,
                                               float* __restrict__ ctx){
  __shared__ float xs[4][1024];
  int bid = blockIdx.x;
  int fq = bid & 3, h = (bid >> 2) & 15, k = bid >> 6;
  int t = threadIdx.x;
  #pragma unroll
  for (int i = 0; i < 4; i++){
    int idx = i*256 + t;
    int b = idx >> 8, e4 = (idx & 255)*4;
    *(f32x4*)&xs[b][e4] = *(const f32x4*)(wrep + ((size_t)(b*KH_) + k*16 + h)*E_ + e4);
  }
  __syncthreads();
  int wv = t >> 6, lane = t & 63;
  #pragma unroll
  for (int r = 0; r < 4; r++){
    int f = h*64 + fq*16 + wv*4 + r;
    const float* wrow = Wv + ((size_t)(k*E_) + f)*E_;
    float a0=0.f, a1=0.f, a2=0.f, a3=0.f;
    #pragma unroll
    for (int j = 0; j < 4; j++){
      int e = (j*64 + lane)*4;
      float4 w = *(const float4*)(wrow + e);
      float4 p;
      p = *(const float4*)&xs[0][e]; a0 += w.x*p.x + w.y*p.y + w.z*p.z + w.w*p.w;
      p = *(const float4*)&xs[1][e]; a1 += w.x*p.x + w.y*p.y + w.z*p.z + w.w*p.w;
      p = *(const float4*)&xs[2][e]; a2 += w.x*p.x + w.y*p.y + w.z*p.z + w.w*p.w;
      p = *(const float4*)&xs[3][e]; a3 += w.x*p.x + w.y*p.y + w.z*p.z + w.w*p.w;
    }
    #pragma unroll
    for (int off = 32; off; off >>= 1){
      a0 += __shfl_down(a0, off); a1 += __shfl_down(a1, off);
      a2 += __shfl_down(a2, off); a3 += __shfl_down(a3, off);
    }
    if (lane == 0){
      float bvv = bv[k*E_ + f];
      ctx[((size_t)(k*B_) + 0)*E_ + f] = a0 + bvv;
      ctx[((size_t)(k*B_) + 1)*E_ + f] = a1 + bvv;
      ctx[((size_t)(k*B_) + 2)*E_ + f] = a2 + bvv;
      ctx[((size_t)(k*B_) + 3)*E_ + f] = a3 + bvv;
    }
  }
}

// ---------------- K7/K8: gemv16 with LDS-staged x -------------------------
// grid 512: k=bid>>6, fg=bid&63 (16 f each). 4 waves x 4 f.
__global__ __launch_bounds__(256) void gemv16(const float* __restrict__ in,
                                              const float* __restrict__ W,
                                              const float* __restrict__ bias,
                                              float* __restrict__ outp){
  __shared__ float xs[4][1024];
  int bid = blockIdx.x;
  int fg = bid & 63, k = bid >> 6;
  int t = threadIdx.x;
  #pragma unroll
  for (int i = 0; i < 4; i++){
    int idx = i*256 + t;
    int b = idx >> 8, e4 = (idx & 255)*4;
    *(f32x4*)&xs[b][e4] = *(const f32x4*)(in + ((size_t)(k*B_) + b)*E_ + e4);
  }
  __syncthreads();
  int wv = t >> 6, lane = t & 63;
  #pragma unroll
  for (int r = 0; r < 4; r++){
    int f = fg*16 + wv*4 + r;
    const float* wrow = W + ((size_t)(k*E_) + f)*E_;
    float a0=0.f, a1=0.f, a2=0.f, a3=0.f;
    #pragma unroll
    for (int j = 0; j < 4; j++){
      int e = (j*64 + lane)*4;
      float4 w = *(const float4*)(wrow + e);
      float4 p;
      p = *(const float4*)&xs[0][e]; a0 += w.x*p.x + w.y*p.y + w.z*p.z + w.w*p.w;
      p = *(const float4*)&xs[1][e]; a1 += w.x*p.x + w.y*p.y + w.z*p.z + w.w*p.w;
      p = *(const float4*)&xs[2][e]; a2 += w.x*p.x + w.y*p.y + w.z*p.z + w.w*p.w;
      p = *(const float4*)&xs[3][e]; a3 += w.x*p.x + w.y*p.y + w.z*p.z + w.w*p.w;
    }
    #pragma unroll
    for (int off = 32; off; off >>= 1){
      a0 += __shfl_down(a0, off); a1 += __shfl_down(a1, off);
      a2 += __shfl_down(a2, off); a3 += __shfl_down(a3, off);
    }
    if (lane == 0){
      float bb = bias[k*E_ + f];
      outp[((size_t)(k*B_) + 0)*E_ + f] = a0 + bb;
      outp[((size_t)(k*B_) + 1)*E_ + f] = a1 + bb;
      outp[((size_t)(k*B_) + 2)*E_ + f] = a2 + bb;
      outp[((size_t)(k*B_) + 3)*E_ + f] = a3 + bb;
    }
  }
}

// ---------------- K9: LayerNorm over E, write d_out[b,k,e] ----------------
__global__ __launch_bounds__(256) void k9_ln(const float* __restrict__ outkb,
                                             const float* __restrict__ gamma,
                                             const float* __restrict__ beta,
                                             float* __restrict__ out){
  __shared__ float rs[4], rs2[4];
  int row = blockIdx.x;            // b*K_ + k
  int b = row >> 3, k = row & 7;
  int t = threadIdx.x, wv = t >> 6, lane = t & 63;
  const float* x = outkb + ((size_t)(k*B_) + b)*E_;
  float4 v = *(const float4*)(x + t*4);
  float s  = v.x + v.y + v.z + v.w;
  float s2 = v.x*v.x + v.y*v.y + v.z*v.z + v.w*v.w;
  #pragma unroll
  for (int off = 32; off; off >>= 1){ s += __shfl_down(s, off); s2 += __shfl_down(s2, off); }
  if (lane == 0){ rs[wv] = s; rs2[wv] = s2; }
  __syncthreads();
  float S  = rs[0] + rs[1] + rs[2] + rs[3];
  float S2 = rs2[0] + rs2[1] + rs2[2] + rs2[3];
  float mu = S * (1.0f/E_);
  float var = S2 * (1.0f/E_) - mu*mu;
  float inv = rsqrtf(var + 1e-5f);
  float4 g  = *(const float4*)(gamma + t*4);
  float4 bt = *(const float4*)(beta + t*4);
  float4 o;
  o.x = g.x*(v.x-mu)*inv + bt.x;
  o.y = g.y*(v.y-mu)*inv + bt.y;
  o.z = g.z*(v.z-mu)*inv + bt.z;
  o.w = g.w*(v.w-mu)*inv + bt.w;
  *(float4*)(out + ((size_t)(b*K_) + k)*E_ + t*4) = o;
}

extern "C" void kernel_launch(void* const* d_in, const int* in_sizes, int n_in,
                              void* d_out, int out_size, void* d_ws, size_t ws_size,
                              hipStream_t stream){
  const float* rep     = (const float*)d_in[0];
  const float* mask    = (const float*)d_in[1];
  const float* queries = (const float*)d_in[2];
  const float* Wq = (const float*)d_in[3];
  const float* bq = (const float*)d_in[4];
  const float* Wk = (const float*)d_in[5];
  const float* bk = (const float*)d_in[6];
  const float* Wv = (const float*)d_in[7];
  const float* bv = (const float*)d_in[8];
  const float* Wo = (const float*)d_in[9];
  const float* bo = (const float*)d_in[10];
  const float* Wp = (const float*)d_in[11];
  const float* bp = (const float*)d_in[12];
  const float* gamma = (const float*)d_in[13];
  const float* beta  = (const float*)d_in[14];
  float* out = (float*)d_out;

  char* ws = (char*)d_ws;
  size_t off = 0;
  float*  qs      = (float*)(ws + off);  off += (size_t)K_*E_*4;          // 32 KB
  ushort* qkb     = (ushort*)(ws + off); off += (size_t)KH_*E_*2;         // 256 KB
  float*  qb      = (float*)(ws + off);  off += 1024;
  ushort* scoresPb= (ushort*)(ws + off); off += (size_t)4*B_*KH_*S_*2;    // 8 MB
  ushort* probs   = (ushort*)(ws + off); off += (size_t)B_*KH_*S_*2;      // 2 MB
  ushort* wrepPb  = (ushort*)(ws + off); off += (size_t)8*B_*KH_*E_*2;    // 8 MB
  float*  wrep    = (float*)(ws + off);  off += (size_t)B_*KH_*E_*4;      // 2 MB
  float*  ctx     = (float*)(ws + off);  off += (size_t)K_*B_*E_*4;
  float*  attn    = (float*)(ws + off);  off += (size_t)K_*B_*E_*4;
  float*  outkb   = (float*)(ws + off);  off += (size_t)K_*B_*E_*4;

  k1_qs     <<<2048, 256, 0, stream>>>(queries, Wq, bq, qs);
  k2_qk     <<<512,  256, 0, stream>>>(qs, Wk, bk, qkb, qb);
  k3_scores <<<512,  256, 0, stream>>>(rep, qkb, scoresPb);
  k4_softmax<<<512,  256, 0, stream>>>(scoresPb, qb, mask, probs);
  k5_wrep   <<<512,  256, 0, stream>>>(probs, rep, wrepPb);
  k6c_comb  <<<256,  256, 0, stream>>>(wrepPb, wrep);
  k6x_ctx   <<<512,  256, 0, stream>>>(wrep, Wv, bv, ctx);
  gemv16    <<<512,  256, 0, stream>>>(ctx, Wo, bo, attn);
  gemv16    <<<512,  256, 0, stream>>>(attn, Wp, bp, outkb);
  k9_ln     <<<32,   256, 0, stream>>>(outkb, gamma, beta, out);
}

// Round 16
// 72.905 us; speedup vs baseline: 18.2315x; 1.0366x over previous
//
#include <hip/hip_runtime.h>
#include <hip/hip_bf16.h>
#include <stdint.h>

#define E_  1024
#define H_  16
#define D_  64
#define K_  8
#define B_  4
#define S_  2048
#define KH_ 128   // K_*H_

typedef __attribute__((ext_vector_type(8))) short   short8;
typedef __attribute__((ext_vector_type(8))) ushort  ushort8;
typedef __attribute__((ext_vector_type(4))) ushort  ushort4v;
typedef __attribute__((ext_vector_type(4))) float   f32x4;

__device__ __forceinline__ ushort f2bf(float x){
  union { float f; uint32_t u; } v; v.f = x;
  return (ushort)((v.u + 0x7FFFu + ((v.u >> 16) & 1u)) >> 16);
}
__device__ __forceinline__ float bf2f(ushort u){
  union { uint32_t u32; float f; } v; v.u32 = ((uint32_t)u) << 16; return v.f;
}

// raw producer barrier: ds_writes visible, but do NOT drain vmcnt (keeps
// the depth-2 global prefetch in flight across the barrier).
__device__ __forceinline__ void lds_barrier(){
  asm volatile("s_waitcnt lgkmcnt(0)" ::: "memory");
  __builtin_amdgcn_s_barrier();
}

// ---------------- K1: qs[k,f] = (queries[k,:]·Wq[k,f,:] + bq)*0.125 -------
__global__ __launch_bounds__(256) void k1_qs(const float* __restrict__ queries,
                                             const float* __restrict__ Wq,
                                             const float* __restrict__ bq,
                                             float* __restrict__ qs){
  int gw = (blockIdx.x * 256 + threadIdx.x) >> 6;
  int lane = threadIdx.x & 63;
  int k = gw >> 10, f = gw & 1023;
  const float* wrow = Wq + ((size_t)(k*E_) + f)*E_;
  const float* qrow = queries + k*E_;
  float acc = 0.f;
  #pragma unroll
  for (int j = 0; j < 4; j++){
    int e = (j*64 + lane)*4;
    float4 w = *(const float4*)(wrow + e);
    float4 q = *(const float4*)(qrow + e);
    acc += w.x*q.x + w.y*q.y + w.z*q.z + w.w*q.w;
  }
  #pragma unroll
  for (int off = 32; off; off >>= 1) acc += __shfl_down(acc, off);
  if (lane == 0) qs[k*E_ + f] = (acc + bq[k*E_ + f]) * 0.125f;
}

// ---------------- K2: qk[k,h,e] (bf16) and qb[k,h] ------------------------
__global__ __launch_bounds__(256) void k2_qk(const float* __restrict__ qs,
                                             const float* __restrict__ Wk,
                                             const float* __restrict__ bk,
                                             ushort* __restrict__ qkb,
                                             float* __restrict__ qb){
  int bid = blockIdx.x;
  int eq = bid & 3;
  int kh = bid >> 2;
  int k = kh >> 4, h = kh & 15;
  __shared__ float qsh[64];
  int t = threadIdx.x;
  if (t < 64) qsh[t] = qs[k*E_ + h*64 + t];
  __syncthreads();
  int e = eq*256 + t;
  const float* wbase = Wk + ((size_t)(k*E_) + h*64)*E_ + e;
  float a = 0.f;
  #pragma unroll 16
  for (int d = 0; d < 64; d++) a += qsh[d] * wbase[(size_t)d*E_];
  qkb[kh*E_ + e] = f2bf(a);
  if (eq == 0 && t == 0){
    float s = 0.f;
    for (int d = 0; d < 64; d++) s += qsh[d] * bk[k*E_ + h*64 + d];
    qb[kh] = s;
  }
}

// ---------------- K3: scoresPb[ks][b,kh,s] partial (bf16) = rep·qk --------
// 512 blocks x 512 thr (8 waves, 2x4): 16 waves/CU. Same tiles/traffic as
// the 256-thr version; work re-partitioned for 2x occupancy.
__global__ __launch_bounds__(512) void k3_scores(const float* __restrict__ rep,
                                                 const ushort* __restrict__ qkb,
                                                 ushort* __restrict__ scoresPb){
  __shared__ __align__(16) ushort As[2][64][40];
  __shared__ __align__(16) ushort Bs[2][128][40];
  int bid = blockIdx.x;
  int ks = bid & 3, m = (bid >> 2) & 31, b = bid >> 7;
  int t = threadIdx.x, wv = t >> 6, lane = t & 63;
  int l0 = lane & 15, l1 = lane >> 4;
  int wr = wv >> 2, wc = wv & 3;                  // 2 (s) x 4 (kh)
  int arow = t >> 3, acg = t & 7;                 // A: 64 rows x 8 col-groups of 4
  int brow = t >> 2, bq8 = t & 3;                 // B: 128 rows x 4 groups of 8
  const float*  aSrc = rep + ((size_t)(b*S_) + m*64 + arow)*E_ + ks*256 + acg*4;
  const ushort* bSrc = qkb + (size_t)brow*E_ + ks*256 + bq8*8;

  f32x4 acc[2][2];
  #pragma unroll
  for (int mt = 0; mt < 2; mt++)
    #pragma unroll
    for (int nt = 0; nt < 2; nt++) acc[mt][nt] = (f32x4){0.f,0.f,0.f,0.f};

  float4  va[2];
  ushort8 vb[2];
  #pragma unroll
  for (int p = 0; p < 2; p++){
    va[p] = *(const float4*)(aSrc + p*32);
    vb[p] = *(const ushort8*)(bSrc + p*32);
  }
  {
    ushort4v u;
    u[0]=f2bf(va[0].x); u[1]=f2bf(va[0].y); u[2]=f2bf(va[0].z); u[3]=f2bf(va[0].w);
    *(ushort4v*)&As[0][arow][acg*4] = u;
    *(ushort8*)&Bs[0][brow][bq8*8] = vb[0];
  }
  lds_barrier();

  #pragma unroll
  for (int c = 0; c < 8; c++){
    const int cur = c & 1;
    short8 af[2], bf[2];
    #pragma unroll
    for (int mt = 0; mt < 2; mt++)
      af[mt] = *(const short8*)&As[cur][wr*32 + mt*16 + l0][l1*8];
    #pragma unroll
    for (int nt = 0; nt < 2; nt++)
      bf[nt] = *(const short8*)&Bs[cur][wc*32 + nt*16 + l0][l1*8];
    #pragma unroll
    for (int mt = 0; mt < 2; mt++)
      #pragma unroll
      for (int nt = 0; nt < 2; nt++)
        acc[mt][nt] = __builtin_amdgcn_mfma_f32_16x16x32_bf16(af[mt], bf[nt], acc[mt][nt], 0,0,0);
    if (c < 6){
      const int p = c & 1;
      va[p] = *(const float4*)(aSrc + (c+2)*32);
      vb[p] = *(const ushort8*)(bSrc + (c+2)*32);
    }
    if (c < 7){
      const int p = (c+1) & 1;
      ushort4v u;
      u[0]=f2bf(va[p].x); u[1]=f2bf(va[p].y); u[2]=f2bf(va[p].z); u[3]=f2bf(va[p].w);
      *(ushort4v*)&As[p][arow][acg*4] = u;
      *(ushort8*)&Bs[p][brow][bq8*8] = vb[p];
    }
    lds_barrier();
  }
  ushort* obase = scoresPb + (size_t)ks*((size_t)B_*KH_*S_) + (size_t)(b*KH_)*S_;
  #pragma unroll
  for (int mt = 0; mt < 2; mt++){
    #pragma unroll
    for (int nt = 0; nt < 2; nt++){
      int kh = wc*32 + nt*16 + l0;
      int s  = m*64 + wr*32 + mt*16 + l1*4;
      ushort4v u;
      u[0] = f2bf(acc[mt][nt][0]);
      u[1] = f2bf(acc[mt][nt][1]);
      u[2] = f2bf(acc[mt][nt][2]);
      u[3] = f2bf(acc[mt][nt][3]);
      *(ushort4v*)(obase + (size_t)kh*S_ + s) = u;
    }
  }
}

// ---------------- K4: softmax over 4 bf16 partials + qb + mask -> probs ---
__global__ __launch_bounds__(256) void k4_softmax(const ushort* __restrict__ scoresPb,
                                                  const float* __restrict__ qb,
                                                  const float* __restrict__ mask,
                                                  ushort* __restrict__ probs){
  __shared__ float red[4];
  const size_t P = (size_t)B_*KH_*S_;
  int row = blockIdx.x;            // b*KH + kh
  int b = row >> 7, kh = row & 127;
  int t = threadIdx.x, wv = t >> 6, lane = t & 63;
  const ushort* x = scoresPb + (size_t)row * S_ + t*8;
  const float* mrow = mask + b*S_ + t*8;
  float qbv = qb[kh];
  float v[8] = {0.f,0.f,0.f,0.f,0.f,0.f,0.f,0.f};
  #pragma unroll
  for (int p = 0; p < 4; p++){
    ushort8 up = *(const ushort8*)(x + (size_t)p*P);
    #pragma unroll
    for (int i = 0; i < 8; i++) v[i] += bf2f(up[i]);
  }
  {
    float4 m0 = *(const float4*)(mrow);
    float4 m1 = *(const float4*)(mrow + 4);
    v[0] += qbv + m0.x; v[1] += qbv + m0.y; v[2] += qbv + m0.z; v[3] += qbv + m0.w;
    v[4] += qbv + m1.x; v[5] += qbv + m1.y; v[6] += qbv + m1.z; v[7] += qbv + m1.w;
  }
  float m = v[0];
  #pragma unroll
  for (int i = 1; i < 8; i++) m = fmaxf(m, v[i]);
  #pragma unroll
  for (int off = 32; off; off >>= 1) m = fmaxf(m, __shfl_down(m, off));
  if (lane == 0) red[wv] = m;
  __syncthreads();
  float M = fmaxf(fmaxf(red[0], red[1]), fmaxf(red[2], red[3]));
  __syncthreads();
  float s = 0.f;
  #pragma unroll
  for (int i = 0; i < 8; i++){ v[i] = __expf(v[i] - M); s += v[i]; }
  #pragma unroll
  for (int off = 32; off; off >>= 1) s += __shfl_down(s, off);
  if (lane == 0) red[wv] = s;
  __syncthreads();
  float inv = 1.0f / (red[0] + red[1] + red[2] + red[3]);
  ushort8 o;
  #pragma unroll
  for (int i = 0; i < 8; i++) o[i] = f2bf(v[i] * inv);
  *(ushort8*)(probs + (size_t)row*S_ + t*8) = o;
}

// ---------------- K5: wrepPb[sp][b,kh,e] (bf16) = probs·rep ---------------
// 512 blocks x 512 thr (8 waves, 4x2): 16 waves/CU. Same tiles/traffic.
__global__ __launch_bounds__(512) void k5_wrep(const ushort* __restrict__ probs,
                                               const float* __restrict__ rep,
                                               ushort* __restrict__ wrepPb){
  __shared__ __align__(16) ushort As[2][128][40];
  __shared__ __align__(16) ushort Bs[2][64][40];
  int bid = blockIdx.x;
  int et = bid & 15, b = (bid >> 4) & 3, sp = bid >> 6;
  int t = threadIdx.x, wv = t >> 6, lane = t & 63;
  int l0 = lane & 15, l1 = lane >> 4;
  int wr = wv >> 1, wc = wv & 1;                  // 4 (kh) x 2 (e)
  int arow = t >> 2, aq8 = t & 3;                 // A: 128 rows x 4 groups of 8
  int bsrow = t >> 4, be = t & 15;                // B: 32 s-rows x 16 groups of 4 e
  const ushort* aSrc = probs + (size_t)(b*KH_ + arow)*S_ + sp*256 + aq8*8;
  const float*  bSrc = rep + ((size_t)(b*S_) + sp*256 + bsrow)*E_ + et*64 + be*4;

  f32x4 acc[2][2];
  #pragma unroll
  for (int mt = 0; mt < 2; mt++)
    #pragma unroll
    for (int nt = 0; nt < 2; nt++) acc[mt][nt] = (f32x4){0.f,0.f,0.f,0.f};

  ushort8 va[2];
  float4  vb[2];
  #pragma unroll
  for (int p = 0; p < 2; p++){
    va[p] = *(const ushort8*)(aSrc + p*32);
    vb[p] = *(const float4*)(bSrc + (size_t)(p*32)*E_);
  }
  {
    *(ushort8*)&As[0][arow][aq8*8] = va[0];
    float vv[4] = {vb[0].x, vb[0].y, vb[0].z, vb[0].w};
    #pragma unroll
    for (int j = 0; j < 4; j++){
      int e = be*4 + j;
      int sw = (bsrow + ((e >> 3) & 3)*8) & 31;
      Bs[0][e][sw] = f2bf(vv[j]);
    }
  }
  lds_barrier();

  #pragma unroll
  for (int c = 0; c < 8; c++){
    const int cur = c & 1;
    short8 af[2], bf[2];
    #pragma unroll
    for (int mt = 0; mt < 2; mt++)
      af[mt] = *(const short8*)&As[cur][wr*32 + mt*16 + l0][l1*8];
    #pragma unroll
    for (int nt = 0; nt < 2; nt++){
      int e_loc = wc*32 + nt*16 + l0;
      int sstart = (l1*8 + ((e_loc >> 3) & 3)*8) & 31;
      bf[nt] = *(const short8*)&Bs[cur][e_loc][sstart];
    }
    #pragma unroll
    for (int mt = 0; mt < 2; mt++)
      #pragma unroll
      for (int nt = 0; nt < 2; nt++)
        acc[mt][nt] = __builtin_amdgcn_mfma_f32_16x16x32_bf16(af[mt], bf[nt], acc[mt][nt], 0,0,0);
    if (c < 6){
      const int p = c & 1;
      va[p] = *(const ushort8*)(aSrc + (c+2)*32);
      vb[p] = *(const float4*)(bSrc + (size_t)((c+2)*32)*E_);
    }
    if (c < 7){
      const int p = (c+1) & 1;
      *(ushort8*)&As[p][arow][aq8*8] = va[p];
      float vv[4] = {vb[p].x, vb[p].y, vb[p].z, vb[p].w};
      #pragma unroll
      for (int j = 0; j < 4; j++){
        int e = be*4 + j;
        int sw = (bsrow + ((e >> 3) & 3)*8) & 31;
        Bs[p][e][sw] = f2bf(vv[j]);
      }
    }
    lds_barrier();
  }
  ushort* obase = wrepPb + (size_t)sp*((size_t)B_*KH_*E_) + (size_t)(b*KH_)*E_ + et*64;
  #pragma unroll
  for (int mt = 0; mt < 2; mt++){
    #pragma unroll
    for (int nt = 0; nt < 2; nt++){
      int kh = wr*32 + mt*16 + l1*4;
      int e  = wc*32 + nt*16 + l0;
      #pragma unroll
      for (int r = 0; r < 4; r++)
        obase[(size_t)(kh + r)*E_ + e] = f2bf(acc[mt][nt][r]);
    }
  }
}

// ---------------- K6c: wrep (f32) = sum of 8 bf16 partials ----------------
__global__ __launch_bounds__(256) void k6c_comb(const ushort* __restrict__ wrepPb,
                                                float* __restrict__ wrep){
  const size_t P = (size_t)B_*KH_*E_;
  size_t i = ((size_t)blockIdx.x * 256 + threadIdx.x) * 8;
  float a[8] = {0.f,0.f,0.f,0.f,0.f,0.f,0.f,0.f};
  #pragma unroll
  for (int p = 0; p < 8; p++){
    ushort8 u = *(const ushort8*)(wrepPb + i + (size_t)p*P);
    #pragma unroll
    for (int j = 0; j < 8; j++) a[j] += bf2f(u[j]);
  }
  f32x4 o0 = {a[0], a[1], a[2], a[3]};
  f32x4 o1 = {a[4], a[5], a[6], a[7]};
  *(f32x4*)(wrep + i)     = o0;
  *(f32x4*)(wrep + i + 4) = o1;
}

// ---------------- K6x: ctx[k,b,f] = wrep[b,kh(f),:]·Wv[k,f,:] + bv --------
// 512 blocks x 512 thr: 16 f-rows/block, 2 f/wave. 16 waves/CU.
__global__ __launch_bounds__(512) void k6x_ctx(const float* __restrict__ wrep,
                                               const float* __restrict__ Wv,
                                               const float* __restrict__ bv,
                                               float* __restrict__ ctx){
  __shared__ float xs[4][1024];
  int bid = blockIdx.x;
  int fq = bid & 3, h = (bid >> 2) & 15, k = bid >> 6;
  int t = threadIdx.x;
  #pragma unroll
  for (int i = 0; i < 2; i++){
    int idx = i*512 + t;
    int b = idx >> 8, e4 = (idx & 255)*4;
    *(f32x4*)&xs[b][e4] = *(const f32x4*)(wrep + ((size_t)(b*KH_) + k*16 + h)*E_ + e4);
  }
  __syncthreads();
  int wv = t >> 6, lane = t & 63;
  #pragma unroll
  for (int r = 0; r < 2; r++){
    int f = h*64 + fq*16 + wv*2 + r;
    const float* wrow = Wv + ((size_t)(k*E_) + f)*E_;
    float a0=0.f, a1=0.f, a2=0.f, a3=0.f;
    #pragma unroll
    for (int j = 0; j < 4; j++){
      int e = (j*64 + lane)*4;
      float4 w = *(const float4*)(wrow + e);
      float4 p;
      p = *(const float4*)&xs[0][e]; a0 += w.x*p.x + w.y*p.y + w.z*p.z + w.w*p.w;
      p = *(const float4*)&xs[1][e]; a1 += w.x*p.x + w.y*p.y + w.z*p.z + w.w*p.w;
      p = *(const float4*)&xs[2][e]; a2 += w.x*p.x + w.y*p.y + w.z*p.z + w.w*p.w;
      p = *(const float4*)&xs[3][e]; a3 += w.x*p.x + w.y*p.y + w.z*p.z + w.w*p.w;
    }
    #pragma unroll
    for (int off = 32; off; off >>= 1){
      a0 += __shfl_down(a0, off); a1 += __shfl_down(a1, off);
      a2 += __shfl_down(a2, off); a3 += __shfl_down(a3, off);
    }
    if (lane == 0){
      float bvv = bv[k*E_ + f];
      ctx[((size_t)(k*B_) + 0)*E_ + f] = a0 + bvv;
      ctx[((size_t)(k*B_) + 1)*E_ + f] = a1 + bvv;
      ctx[((size_t)(k*B_) + 2)*E_ + f] = a2 + bvv;
      ctx[((size_t)(k*B_) + 3)*E_ + f] = a3 + bvv;
    }
  }
}

// ---------------- K7/K8: gemv16 with LDS-staged x, 512 thr ----------------
__global__ __launch_bounds__(512) void gemv16(const float* __restrict__ in,
                                              const float* __restrict__ W,
                                              const float* __restrict__ bias,
                                              float* __restrict__ outp){
  __shared__ float xs[4][1024];
  int bid = blockIdx.x;
  int fg = bid & 63, k = bid >> 6;
  int t = threadIdx.x;
  #pragma unroll
  for (int i = 0; i < 2; i++){
    int idx = i*512 + t;
    int b = idx >> 8, e4 = (idx & 255)*4;
    *(f32x4*)&xs[b][e4] = *(const f32x4*)(in + ((size_t)(k*B_) + b)*E_ + e4);
  }
  __syncthreads();
  int wv = t >> 6, lane = t & 63;
  #pragma unroll
  for (int r = 0; r < 2; r++){
    int f = fg*16 + wv*2 + r;
    const float* wrow = W + ((size_t)(k*E_) + f)*E_;
    float a0=0.f, a1=0.f, a2=0.f, a3=0.f;
    #pragma unroll
    for (int j = 0; j < 4; j++){
      int e = (j*64 + lane)*4;
      float4 w = *(const float4*)(wrow + e);
      float4 p;
      p = *(const float4*)&xs[0][e]; a0 += w.x*p.x + w.y*p.y + w.z*p.z + w.w*p.w;
      p = *(const float4*)&xs[1][e]; a1 += w.x*p.x + w.y*p.y + w.z*p.z + w.w*p.w;
      p = *(const float4*)&xs[2][e]; a2 += w.x*p.x + w.y*p.y + w.z*p.z + w.w*p.w;
      p = *(const float4*)&xs[3][e]; a3 += w.x*p.x + w.y*p.y + w.z*p.z + w.w*p.w;
    }
    #pragma unroll
    for (int off = 32; off; off >>= 1){
      a0 += __shfl_down(a0, off); a1 += __shfl_down(a1, off);
      a2 += __shfl_down(a2, off); a3 += __shfl_down(a3, off);
    }
    if (lane == 0){
      float bb = bias[k*E_ + f];
      outp[((size_t)(k*B_) + 0)*E_ + f] = a0 + bb;
      outp[((size_t)(k*B_) + 1)*E_ + f] = a1 + bb;
      outp[((size_t)(k*B_) + 2)*E_ + f] = a2 + bb;
      outp[((size_t)(k*B_) + 3)*E_ + f] = a3 + bb;
    }
  }
}

// ---------------- K9: LayerNorm over E, write d_out[b,k,e] ----------------
__global__ __launch_bounds__(256) void k9_ln(const float* __restrict__ outkb,
                                             const float* __restrict__ gamma,
                                             const float* __restrict__ beta,
                                             float* __restrict__ out){
  __shared__ float rs[4], rs2[4];
  int row = blockIdx.x;            // b*K_ + k
  int b = row >> 3, k = row & 7;
  int t = threadIdx.x, wv = t >> 6, lane = t & 63;
  const float* x = outkb + ((size_t)(k*B_) + b)*E_;
  float4 v = *(const float4*)(x + t*4);
  float s  = v.x + v.y + v.z + v.w;
  float s2 = v.x*v.x + v.y*v.y + v.z*v.z + v.w*v.w;
  #pragma unroll
  for (int off = 32; off; off >>= 1){ s += __shfl_down(s, off); s2 += __shfl_down(s2, off); }
  if (lane == 0){ rs[wv] = s; rs2[wv] = s2; }
  __syncthreads();
  float S  = rs[0] + rs[1] + rs[2] + rs[3];
  float S2 = rs2[0] + rs2[1] + rs2[2] + rs2[3];
  float mu = S * (1.0f/E_);
  float var = S2 * (1.0f/E_) - mu*mu;
  float inv = rsqrtf(var + 1e-5f);
  float4 g  = *(const float4*)(gamma + t*4);
  float4 bt = *(const float4*)(beta + t*4);
  float4 o;
  o.x = g.x*(v.x-mu)*inv + bt.x;
  o.y = g.y*(v.y-mu)*inv + bt.y;
  o.z = g.z*(v.z-mu)*inv + bt.z;
  o.w = g.w*(v.w-mu)*inv + bt.w;
  *(float4*)(out + ((size_t)(b*K_) + k)*E_ + t*4) = o;
}

extern "C" void kernel_launch(void* const* d_in, const int* in_sizes, int n_in,
                              void* d_out, int out_size, void* d_ws, size_t ws_size,
                              hipStream_t stream){
  const float* rep     = (const float*)d_in[0];
  const float* mask    = (const float*)d_in[1];
  const float* queries = (const float*)d_in[2];
  const float* Wq = (const float*)d_in[3];
  const float* bq = (const float*)d_in[4];
  const float* Wk = (const float*)d_in[5];
  const float* bk = (const float*)d_in[6];
  const float* Wv = (const float*)d_in[7];
  const float* bv = (const float*)d_in[8];
  const float* Wo = (const float*)d_in[9];
  const float* bo = (const float*)d_in[10];
  const float* Wp = (const float*)d_in[11];
  const float* bp = (const float*)d_in[12];
  const float* gamma = (const float*)d_in[13];
  const float* beta  = (const float*)d_in[14];
  float* out = (float*)d_out;

  char* ws = (char*)d_ws;
  size_t off = 0;
  float*  qs      = (float*)(ws + off);  off += (size_t)K_*E_*4;          // 32 KB
  ushort* qkb     = (ushort*)(ws + off); off += (size_t)KH_*E_*2;         // 256 KB
  float*  qb      = (float*)(ws + off);  off += 1024;
  ushort* scoresPb= (ushort*)(ws + off); off += (size_t)4*B_*KH_*S_*2;    // 8 MB
  ushort* probs   = (ushort*)(ws + off); off += (size_t)B_*KH_*S_*2;      // 2 MB
  ushort* wrepPb  = (ushort*)(ws + off); off += (size_t)8*B_*KH_*E_*2;    // 8 MB
  float*  wrep    = (float*)(ws + off);  off += (size_t)B_*KH_*E_*4;      // 2 MB
  float*  ctx     = (float*)(ws + off);  off += (size_t)K_*B_*E_*4;
  float*  attn    = (float*)(ws + off);  off += (size_t)K_*B_*E_*4;
  float*  outkb   = (float*)(ws + off);  off += (size_t)K_*B_*E_*4;

  k1_qs     <<<2048, 256, 0, stream>>>(queries, Wq, bq, qs);
  k2_qk     <<<512,  256, 0, stream>>>(qs, Wk, bk, qkb, qb);
  k3_scores <<<512,  512, 0, stream>>>(rep, qkb, scoresPb);
  k4_softmax<<<512,  256, 0, stream>>>(scoresPb, qb, mask, probs);
  k5_wrep   <<<512,  512, 0, stream>>>(probs, rep, wrepPb);
  k6c_comb  <<<256,  256, 0, stream>>>(wrepPb, wrep);
  k6x_ctx   <<<512,  512, 0, stream>>>(wrep, Wv, bv, ctx);
  gemv16    <<<512,  512, 0, stream>>>(ctx, Wo, bo, attn);
  gemv16    <<<512,  512, 0, stream>>>(attn, Wp, bp, outkb);
  k9_ln     <<<32,   256, 0, stream>>>(outkb, gamma, beta, out);
}